// Round 7
// baseline (144.514 us; speedup 1.0000x reference)
//
#include <hip/hip_runtime.h>
#include <hip/hip_bf16.h>

typedef float f32x4 __attribute__((ext_vector_type(4)));
typedef short s16x8 __attribute__((ext_vector_type(8)));

#define LOG2_N 2.887525271f   // log2(7.4)
#define HALF_N 3.7f           // n_param / 2

// ---------------- kernel 1: A[m,k] = 3.7 * clip(x,0,1)^log2(7.4)  (bf16) ----
__global__ __launch_bounds__(256) void fv_kernel(const float* __restrict__ x,
                                                 __hip_bfloat16* __restrict__ a,
                                                 int total4) {
  int i = blockIdx.x * blockDim.x + threadIdx.x;
  if (i >= total4) return;
  float4 v = reinterpret_cast<const float4*>(x)[i];
  const float* vp = reinterpret_cast<const float*>(&v);
  union { ushort4 u4; ushort s[4]; } o;
#pragma unroll
  for (int j = 0; j < 4; ++j) {
    float xc = fminf(fmaxf(vp[j], 0.0f), 1.0f);
    float r = (xc > 0.0f) ? HALF_N * exp2f(LOG2_N * __log2f(xc)) : 0.0f;
    __hip_bfloat16 h = __float2bfloat16(r);
    o.s[j] = *reinterpret_cast<ushort*>(&h);
  }
  reinterpret_cast<ushort4*>(a)[i] = o.u4;
}

// ---------------- kernel 2: WT[n][k] = bf16(w[k][n]) ------------------------
__global__ __launch_bounds__(256) void wt_kernel(const float* __restrict__ w,
                                                 __hip_bfloat16* __restrict__ wt,
                                                 int K, int N) {
  __shared__ float tile[64][65];
  const int n0 = blockIdx.x * 64;
  const int k0 = blockIdx.y * 64;
  const int tid = threadIdx.x;
#pragma unroll
  for (int i = 0; i < 16; ++i) {
    const int lin = i * 256 + tid;
    const int r = lin >> 6;   // k within tile
    const int c = lin & 63;   // n within tile
    tile[r][c] = w[(size_t)(k0 + r) * N + (n0 + c)];
  }
  __syncthreads();
  const int kk = (tid & 31) * 2;  // 0..62, even
  const int r0 = tid >> 5;        // 0..7
#pragma unroll
  for (int i = 0; i < 8; ++i) {
    const int r = r0 + i * 8;     // n within tile
    __hip_bfloat16 h0 = __float2bfloat16(tile[kk][r]);
    __hip_bfloat16 h1 = __float2bfloat16(tile[kk + 1][r]);
    ushort2 u;
    u.x = *reinterpret_cast<ushort*>(&h0);
    u.y = *reinterpret_cast<ushort*>(&h1);
    *reinterpret_cast<ushort2*>(&wt[(size_t)(n0 + r) * K + (k0 + kk)]) = u;
  }
}

// ---------------- kernel 2b: C init = 3.7 * bias ----------------------------
__global__ __launch_bounds__(256) void cinit_kernel(const float* __restrict__ b,
                                                    float* __restrict__ y,
                                                    int nq, int total4) {
  int i = blockIdx.x * blockDim.x + threadIdx.x;
  if (i >= total4) return;
  float4 bv = reinterpret_cast<const float4*>(b)[i & (nq - 1)];
  bv.x *= HALF_N; bv.y *= HALF_N; bv.z *= HALF_N; bv.w *= HALF_N;
  reinterpret_cast<float4*>(y)[i] = bv;
}

// -- kernel 3: K-split GEMM. 512 blocks (16x16 tiles x 2 K-halves), 4 waves, -
// -- wave tile 128x64, BK=32, 3-buf 72 KB LDS -> 2 async blocks per CU. ------
#define BM 128
#define BN 256
#define BK 32
#define TILE_USH 12288   // ushorts per buffer (24 KB): A[128][32] + B[256][32]
#define B_OFF 4096

#define GLD16(g, l)                                              \
  __builtin_amdgcn_global_load_lds(                              \
      (const __attribute__((address_space(1))) void*)(g),        \
      (__attribute__((address_space(3))) void*)(l), 16, 0, 0)

__global__ __launch_bounds__(256, 2) void gemm_kernel(
    const __hip_bfloat16* __restrict__ A,   // [M][K] bf16
    const __hip_bfloat16* __restrict__ BT,  // [N][K] bf16
    float* __restrict__ C,                  // [M][N], pre-init with 3.7*bias
    int M, int N, int K) {
  __shared__ ushort lds[3 * TILE_USH];   // 72 KB

  const int NTM = M / BM;               // 16
  const int NTN = N / BN;               // 16
  const int nwg = NTM * NTN * 2;        // 512 (x2 K-split)

  // XCD-aware bijective swizzle; kh-partners adjacent -> same XCD L2
  int wg = (int)blockIdx.x;
  wg = (wg & 7) * (nwg >> 3) + (wg >> 3);
  const int kh = wg & 1;
  const int tile = wg >> 1;
  const int nt = tile / NTM;
  const int mt = tile % NTM;
  const int m0 = mt * BM;
  const int n0 = nt * BN;
  const int k0 = kh * (K / 2);          // this block's K-range base

  const int tid = threadIdx.x;
  const int lane = tid & 63;
  const int wid = tid >> 6;   // 0..3; wave owns cols wid*64..+63, rows 0..127

  const ushort* Au = (const ushort*)A;
  const ushort* Bu = (const ushort*)BT;

  // ---- staging (pre-swizzled global source, linear LDS dest) ----
  // LDS[r][c16'] = global[r][c16' ^ ((r>>1)&3)]; rows are 32 ushorts (64 B).
  // Each gld_lds chunk = 16 rows: lane l -> row base+(l>>2), c16' = l&3,
  // so source c16 = (l&3) ^ ((l>>3)&3).
  const int lrow = lane >> 2;
  const int lc8 = ((lane & 3) ^ ((lane >> 3) & 3)) * 8;  // ushort offset
  // wave handles 6 of 24 chunks: c = wid*6 + j
  const ushort* srcP[6];
  int dstOff[6];
#pragma unroll
  for (int j = 0; j < 6; ++j) {
    const int c = wid * 6 + j;
    if (c < 8) {   // A chunk: rows c*16..+15
      srcP[j] = Au + (size_t)(m0 + c * 16 + lrow) * K + k0 + lc8;
      dstOff[j] = c * 512;
    } else {       // B chunk
      srcP[j] = Bu + (size_t)(n0 + (c - 8) * 16 + lrow) * K + k0 + lc8;
      dstOff[j] = B_OFF + (c - 8) * 512;
    }
  }

  auto stage = [&](ushort* L, int t) {   // 6 gld_lds per wave = 6 KB
#pragma unroll
    for (int j = 0; j < 6; ++j)
      GLD16(srcP[j] + (size_t)t * BK, L + dstOff[j]);
  };

  // ---- fragment read addressing (swizzled ds_read, 2-way = free) ----
  const int frow = lane & 15;
  const int c16p = (lane >> 4) ^ ((frow >> 1) & 3);
  const int aOff = frow * 32 + c16p * 8;                     // + mi*512
  const int bOff = B_OFF + (wid * 64 + frow) * 32 + c16p * 8;  // + ni*512

  f32x4 acc[8][4];
#pragma unroll
  for (int i = 0; i < 8; ++i)
#pragma unroll
    for (int j = 0; j < 4; ++j)
#pragma unroll
      for (int r = 0; r < 4; ++r) acc[i][j][r] = 0.0f;

  // prologue: stage tiles 0,1; counted wait for tile 0 only
  stage(lds, 0);
  stage(lds + TILE_USH, 1);
  asm volatile("s_waitcnt vmcnt(6)" ::: "memory");
  __builtin_amdgcn_s_barrier();

  const int NT = (K / 2) / BK;   // 64
  int cur = 0;
  for (int t = 0; t < NT; ++t) {
    ushort* ldsCur = lds + cur * TILE_USH;
    int nx = cur + 2; if (nx >= 3) nx -= 3;
    const bool pf = (t + 2 < NT);
    s16x8 a[8], b[4];
#pragma unroll
    for (int mi = 0; mi < 8; ++mi)
      a[mi] = *(const s16x8*)&ldsCur[aOff + mi * 512];
#pragma unroll
    for (int ni = 0; ni < 4; ++ni)
      b[ni] = *(const s16x8*)&ldsCur[bOff + ni * 512];
    if (pf) stage(lds + nx * TILE_USH, t + 2);
    __builtin_amdgcn_s_setprio(1);
#pragma unroll
    for (int mi = 0; mi < 8; ++mi)
#pragma unroll
      for (int ni = 0; ni < 4; ++ni)
        acc[mi][ni] = __builtin_amdgcn_mfma_f32_16x16x32_bf16(
            a[mi], b[ni], acc[mi][ni], 0, 0, 0);
    __builtin_amdgcn_s_setprio(0);
    // counted: only t+2's 6 loads may remain in flight; t+1 guaranteed landed
    if (pf)              asm volatile("s_waitcnt vmcnt(6)" ::: "memory");
    else if (t + 1 < NT) asm volatile("s_waitcnt vmcnt(0)" ::: "memory");
    __builtin_amdgcn_s_barrier();
    cur = cur + 1; if (cur == 3) cur = 0;
  }

  // ---- epilogue: atomic accumulate partial into pre-biased C ----
  const int ccol = lane & 15;
  const int crow = (lane >> 4) * 4;
#pragma unroll
  for (int ni = 0; ni < 4; ++ni) {
    const int gc = n0 + wid * 64 + ni * 16 + ccol;
#pragma unroll
    for (int mi = 0; mi < 8; ++mi) {
      const int gr = m0 + mi * 16 + crow;
#pragma unroll
      for (int r = 0; r < 4; ++r)
        unsafeAtomicAdd(&C[(size_t)(gr + r) * N + gc], acc[mi][ni][r]);
    }
  }
}

extern "C" void kernel_launch(void* const* d_in, const int* in_sizes, int n_in,
                              void* d_out, int out_size, void* d_ws, size_t ws_size,
                              hipStream_t stream) {
  const float* x = (const float*)d_in[0];
  const float* w = (const float*)d_in[1];
  const float* b = (const float*)d_in[2];
  float* y = (float*)d_out;

  const int N = in_sizes[2];             // 4096
  const int K = in_sizes[1] / N;         // 4096
  const int M = in_sizes[0] / K;         // 2048

  __hip_bfloat16* Abf = (__hip_bfloat16*)d_ws;
  __hip_bfloat16* WT  = (__hip_bfloat16*)((char*)d_ws + (size_t)M * K * 2);
  if (ws_size < (size_t)M * K * 2 + (size_t)N * K * 2) return;  // need 48 MB

  // 1) A = 3.7 * clip(x)^log2(7.4) in bf16
  const int total4 = (M * K) / 4;
  fv_kernel<<<(total4 + 255) / 256, 256, 0, stream>>>(x, Abf, total4);

  // 2) WT = transpose(w) in bf16
  wt_kernel<<<dim3(N / 64, K / 64), dim3(256), 0, stream>>>(w, WT, K, N);

  // 2b) C = 3.7 * bias (broadcast rows)
  const int ct4 = (M * N) / 4;
  cinit_kernel<<<(ct4 + 255) / 256, 256, 0, stream>>>(b, y, N / 4, ct4);

  // 3) y += A @ w  (two K-half blocks per tile, atomic accumulate)
  const int grid = (M / BM) * (N / BN) * 2;
  gemm_kernel<<<grid, 256, 0, stream>>>(Abf, WT, y, M, N, K);
}

// Round 8
// 141.838 us; speedup vs baseline: 1.0189x; 1.0189x over previous
//
#include <hip/hip_runtime.h>
#include <hip/hip_bf16.h>

typedef float f32x4 __attribute__((ext_vector_type(4)));
typedef short s16x8 __attribute__((ext_vector_type(8)));

#define LOG2_N 2.887525271f   // log2(7.4)
#define HALF_N 3.7f           // n_param / 2

// ---------------- kernel 1: A[m,k] = 3.7 * clip(x,0,1)^log2(7.4)  (bf16) ----
__global__ __launch_bounds__(256) void fv_kernel(const float* __restrict__ x,
                                                 __hip_bfloat16* __restrict__ a,
                                                 int total4) {
  int i = blockIdx.x * blockDim.x + threadIdx.x;
  if (i >= total4) return;
  float4 v = reinterpret_cast<const float4*>(x)[i];
  const float* vp = reinterpret_cast<const float*>(&v);
  union { ushort4 u4; ushort s[4]; } o;
#pragma unroll
  for (int j = 0; j < 4; ++j) {
    float xc = fminf(fmaxf(vp[j], 0.0f), 1.0f);
    float r = (xc > 0.0f) ? HALF_N * exp2f(LOG2_N * __log2f(xc)) : 0.0f;
    __hip_bfloat16 h = __float2bfloat16(r);
    o.s[j] = *reinterpret_cast<ushort*>(&h);
  }
  reinterpret_cast<ushort4*>(a)[i] = o.u4;
}

// ---------------- kernel 2: WT[n][k] = bf16(w[k][n]) ------------------------
__global__ __launch_bounds__(256) void wt_kernel(const float* __restrict__ w,
                                                 __hip_bfloat16* __restrict__ wt,
                                                 int K, int N) {
  __shared__ float tile[64][65];
  const int n0 = blockIdx.x * 64;
  const int k0 = blockIdx.y * 64;
  const int tid = threadIdx.x;
#pragma unroll
  for (int i = 0; i < 16; ++i) {
    const int lin = i * 256 + tid;
    const int r = lin >> 6;   // k within tile
    const int c = lin & 63;   // n within tile
    tile[r][c] = w[(size_t)(k0 + r) * N + (n0 + c)];
  }
  __syncthreads();
  const int kk = (tid & 31) * 2;  // 0..62, even
  const int r0 = tid >> 5;        // 0..7
#pragma unroll
  for (int i = 0; i < 8; ++i) {
    const int r = r0 + i * 8;     // n within tile
    __hip_bfloat16 h0 = __float2bfloat16(tile[kk][r]);
    __hip_bfloat16 h1 = __float2bfloat16(tile[kk + 1][r]);
    ushort2 u;
    u.x = *reinterpret_cast<ushort*>(&h0);
    u.y = *reinterpret_cast<ushort*>(&h1);
    *reinterpret_cast<ushort2*>(&wt[(size_t)(n0 + r) * K + (k0 + kk)]) = u;
  }
}

// ---------------- kernel 2b: C init = 3.7 * bias ----------------------------
__global__ __launch_bounds__(256) void cinit_kernel(const float* __restrict__ b,
                                                    float* __restrict__ y,
                                                    int nq, int total4) {
  int i = blockIdx.x * blockDim.x + threadIdx.x;
  if (i >= total4) return;
  float4 bv = reinterpret_cast<const float4*>(b)[i & (nq - 1)];
  bv.x *= HALF_N; bv.y *= HALF_N; bv.z *= HALF_N; bv.w *= HALF_N;
  reinterpret_cast<float4*>(y)[i] = bv;
}

// -- kernel 3: 256x256 8-phase half-K slot-ring GEMM (m201-style), K-split 2 -
// LDS: 4 slots x (A[256][32] + B[256][32]) bf16 = 128 KB.
// slot s = buf*2 + kk;  buf0 holds even K-tiles, buf1 odd (static mapping).
#define BM 256
#define BN 256
#define BK 64
#define SLOT_USH 16384   // 32 KB per slot (A half 16 KB + B half 16 KB)
#define BH_OFF 8192      // B within slot (ushort)

#define GLD16(g, l)                                              \
  __builtin_amdgcn_global_load_lds(                              \
      (const __attribute__((address_space(1))) void*)(g),        \
      (__attribute__((address_space(3))) void*)(l), 16, 0, 0)

__global__ __launch_bounds__(512, 2) void gemm_kernel(
    const __hip_bfloat16* __restrict__ A,   // [M][K] bf16
    const __hip_bfloat16* __restrict__ BT,  // [N][K] bf16
    float* __restrict__ C,                  // [M][N], pre-init with 3.7*bias
    int M, int N, int K) {
  __shared__ ushort lds[4 * SLOT_USH];   // 128 KB

  const int NTM = M / BM;               // 8
  const int NTN = N / BN;               // 16
  const int nwg = NTM * NTN * 2;        // 256 (x2 K-split)

  // XCD-aware bijective swizzle; K-split partners adjacent -> same XCD L2
  int wg = (int)blockIdx.x;
  wg = (wg & 7) * (nwg >> 3) + (wg >> 3);
  const int kh = wg & 1;
  const int tl = wg >> 1;
  const int mt = tl % NTM;
  const int nt = tl / NTM;
  const int m0 = mt * BM;
  const int n0 = nt * BN;
  const int k0b = kh * (K / 2);         // this block's K-range base

  const int tid = threadIdx.x;
  const int lane = tid & 63;
  const int wid = tid >> 6;   // 0..7
  const int wr = wid >> 2;    // 0..1  M-half; wave tile 128x64
  const int wc = wid & 3;     // 0..3  N-quarter

  const ushort* Au = (const ushort*)A;
  const ushort* Bu = (const ushort*)BT;

  // ---- staging: linear LDS dest, pre-swizzled global source ----
  // slot row r (64 B = 4x16B groups): LDS c16' holds data col c16' ^ ((r>>1)&3)
  // gld_lds chunk = 16 rows; lane l -> row chunk*16 + (l>>2), dest c16 = l&3,
  // source c16 = (l&3) ^ ((l>>3)&3).
  const int c16s = ((lane & 3) ^ ((lane >> 3) & 3)) * 8;  // ushort offset
  const ushort* aStage = Au + (size_t)(m0 + wid * 32 + (lane >> 2)) * K + k0b + c16s;
  const ushort* bStage = Bu + (size_t)(n0 + wid * 32 + (lane >> 2)) * K + k0b + c16s;
  const int d0 = (wid * 2) * 512;       // dest ushort offset of chunk i=0

  // stage event: one (tile, khalf) pair of A+B halves = 4 gld_lds / thread
  auto SE = [&](int slot, int t, int kk) {
    ushort* base = &lds[slot * SLOT_USH];
    const size_t off = (size_t)(t * BK + kk * 32);
    GLD16(aStage + off,                  base + d0);
    GLD16(aStage + off + (size_t)16 * K, base + d0 + 512);
    GLD16(bStage + off,                  base + BH_OFF + d0);
    GLD16(bStage + off + (size_t)16 * K, base + BH_OFF + d0 + 512);
  };

  // ---- fragment read addressing (swizzled, 2 lanes/bank = free) ----
  const int frow = lane & 15;
  const int c16p = ((lane >> 4) ^ ((frow >> 1) & 3)) * 8;  // ushort offset
  const int aBase = (wr * 128 + frow) * 32 + c16p;   // + qm*2048 + mi*512
  const int bBase = BH_OFF + (wc * 64 + frow) * 32 + c16p;  // + ni*512

  f32x4 acc[8][4];
#pragma unroll
  for (int i = 0; i < 8; ++i)
#pragma unroll
    for (int j = 0; j < 4; ++j)
#pragma unroll
      for (int r = 0; r < 4; ++r) acc[i][j][r] = 0.0f;

  const int NTT = (K / 2) / BK;   // 32 K-tiles per block
  const int ITERS = NTT / 2;      // 16

  // prologue: t0.k0 -> slot0, t0.k1 -> slot1, t1.k0 -> slot2; counted wait
  SE(0, 0, 0);
  SE(1, 0, 1);
  SE(2, 1, 0);
  asm volatile("s_waitcnt vmcnt(8)" ::: "memory");
  __builtin_amdgcn_s_barrier();

  s16x8 a[4], b[4];

#define READ_AB(slot, qm)                                                   \
  {                                                                         \
    const ushort* SB = &lds[(slot) * SLOT_USH];                             \
    _Pragma("unroll") for (int mi = 0; mi < 4; ++mi)                        \
        a[mi] = *(const s16x8*)&SB[aBase + (qm) * 2048 + mi * 512];         \
    _Pragma("unroll") for (int ni = 0; ni < 4; ++ni)                        \
        b[ni] = *(const s16x8*)&SB[bBase + ni * 512];                       \
  }
#define READ_A(slot, qm)                                                    \
  {                                                                         \
    const ushort* SB = &lds[(slot) * SLOT_USH];                             \
    _Pragma("unroll") for (int mi = 0; mi < 4; ++mi)                        \
        a[mi] = *(const s16x8*)&SB[aBase + (qm) * 2048 + mi * 512];         \
  }
#define DO_MFMA(qm)                                                         \
  __builtin_amdgcn_s_barrier();                                             \
  asm volatile("s_waitcnt lgkmcnt(0)" ::: "memory");                        \
  __builtin_amdgcn_sched_barrier(0);                                        \
  __builtin_amdgcn_s_setprio(1);                                            \
  _Pragma("unroll") for (int mi = 0; mi < 4; ++mi)                          \
      _Pragma("unroll") for (int ni = 0; ni < 4; ++ni)                      \
          acc[(qm) * 4 + mi][ni] = __builtin_amdgcn_mfma_f32_16x16x32_bf16( \
              a[mi], b[ni], acc[(qm) * 4 + mi][ni], 0, 0, 0);               \
  __builtin_amdgcn_s_setprio(0);
#define VM8 asm volatile("s_waitcnt vmcnt(8)" ::: "memory");
#define BAR __builtin_amdgcn_s_barrier();

  for (int i = 0; i < ITERS; ++i) {
    const int T = 2 * i;
    const bool more = (i + 1 < ITERS);
    // ph1: (T,k0,qm0) from slot0
    READ_AB(0, 0);                 DO_MFMA(0); BAR;
    // ph2: (T,k0,qm1); stage (T+1).k1 -> slot3
    READ_A(0, 1); SE(3, T + 1, 1); DO_MFMA(1); VM8; BAR;
    // ph3: (T,k1,qm0) from slot1
    READ_AB(1, 0);                 DO_MFMA(0); BAR;
    // ph4: (T,k1,qm1); stage (T+2).k0 -> slot0
    READ_A(1, 1); if (more) SE(0, T + 2, 0); DO_MFMA(1); VM8; BAR;
    // ph5: (T+1,k0,qm0) from slot2
    READ_AB(2, 0);                 DO_MFMA(0); BAR;
    // ph6: (T+1,k0,qm1); stage (T+2).k1 -> slot1
    READ_A(2, 1); if (more) SE(1, T + 2, 1); DO_MFMA(1); VM8; BAR;
    // ph7: (T+1,k1,qm0) from slot3
    READ_AB(3, 0);                 DO_MFMA(0); BAR;
    // ph8: (T+1,k1,qm1); stage (T+3).k0 -> slot2
    READ_A(3, 1); if (more) SE(2, T + 3, 0); DO_MFMA(1); VM8; BAR;
  }

  // ---- epilogue: atomic accumulate partial into pre-biased C ----
  const int ccol = lane & 15;
  const int crow = (lane >> 4) * 4;
#pragma unroll
  for (int ni = 0; ni < 4; ++ni) {
    const int gc = n0 + wc * 64 + ni * 16 + ccol;
#pragma unroll
    for (int mi = 0; mi < 8; ++mi) {
      const int gr = m0 + wr * 128 + mi * 16 + crow;
#pragma unroll
      for (int r = 0; r < 4; ++r)
        unsafeAtomicAdd(&C[(size_t)(gr + r) * N + gc], acc[mi][ni][r]);
    }
  }
#undef READ_AB
#undef READ_A
#undef DO_MFMA
#undef VM8
#undef BAR
}

extern "C" void kernel_launch(void* const* d_in, const int* in_sizes, int n_in,
                              void* d_out, int out_size, void* d_ws, size_t ws_size,
                              hipStream_t stream) {
  const float* x = (const float*)d_in[0];
  const float* w = (const float*)d_in[1];
  const float* b = (const float*)d_in[2];
  float* y = (float*)d_out;

  const int N = in_sizes[2];             // 4096
  const int K = in_sizes[1] / N;         // 4096
  const int M = in_sizes[0] / K;         // 2048

  __hip_bfloat16* Abf = (__hip_bfloat16*)d_ws;
  __hip_bfloat16* WT  = (__hip_bfloat16*)((char*)d_ws + (size_t)M * K * 2);
  if (ws_size < (size_t)M * K * 2 + (size_t)N * K * 2) return;  // need 48 MB

  // 1) A = 3.7 * clip(x)^log2(7.4) in bf16
  const int total4 = (M * K) / 4;
  fv_kernel<<<(total4 + 255) / 256, 256, 0, stream>>>(x, Abf, total4);

  // 2) WT = transpose(w) in bf16
  wt_kernel<<<dim3(N / 64, K / 64), dim3(256), 0, stream>>>(w, WT, K, N);

  // 2b) C = 3.7 * bias (broadcast rows)
  const int ct4 = (M * N) / 4;
  cinit_kernel<<<(ct4 + 255) / 256, 256, 0, stream>>>(b, y, N / 4, ct4);

  // 3) y += A @ w  (256x256 tiles, K-split 2, atomic accumulate)
  const int grid = (M / BM) * (N / BN) * 2;
  gemm_kernel<<<grid, 512, 0, stream>>>(Abf, WT, y, M, N, K);
}

// Round 9
// 94.589 us; speedup vs baseline: 1.5278x; 1.4995x over previous
//
#include <hip/hip_runtime.h>
#include <hip/hip_bf16.h>

typedef float f32x4 __attribute__((ext_vector_type(4)));
typedef short s16x8 __attribute__((ext_vector_type(8)));

#define LOG2_N 2.887525271f   // log2(7.4)
#define HALF_N 3.7f           // n_param / 2

// ---------------- kernel 1: A[m,k] = 3.7 * clip(x,0,1)^log2(7.4)  (bf16) ----
__global__ __launch_bounds__(256) void fv_kernel(const float* __restrict__ x,
                                                 __hip_bfloat16* __restrict__ a,
                                                 int total4) {
  int i = blockIdx.x * blockDim.x + threadIdx.x;
  if (i >= total4) return;
  float4 v = reinterpret_cast<const float4*>(x)[i];
  const float* vp = reinterpret_cast<const float*>(&v);
  union { ushort4 u4; ushort s[4]; } o;
#pragma unroll
  for (int j = 0; j < 4; ++j) {
    float xc = fminf(fmaxf(vp[j], 0.0f), 1.0f);
    float r = (xc > 0.0f) ? HALF_N * exp2f(LOG2_N * __log2f(xc)) : 0.0f;
    __hip_bfloat16 h = __float2bfloat16(r);
    o.s[j] = *reinterpret_cast<ushort*>(&h);
  }
  reinterpret_cast<ushort4*>(a)[i] = o.u4;
}

// ---------------- kernel 2: WT[n][k] = bf16(w[k][n]) ------------------------
__global__ __launch_bounds__(256) void wt_kernel(const float* __restrict__ w,
                                                 __hip_bfloat16* __restrict__ wt,
                                                 int K, int N) {
  __shared__ float tile[64][65];
  const int n0 = blockIdx.x * 64;
  const int k0 = blockIdx.y * 64;
  const int tid = threadIdx.x;
#pragma unroll
  for (int i = 0; i < 16; ++i) {
    const int lin = i * 256 + tid;
    const int r = lin >> 6;   // k within tile
    const int c = lin & 63;   // n within tile
    tile[r][c] = w[(size_t)(k0 + r) * N + (n0 + c)];
  }
  __syncthreads();
  const int kk = (tid & 31) * 2;  // 0..62, even
  const int r0 = tid >> 5;        // 0..7
#pragma unroll
  for (int i = 0; i < 8; ++i) {
    const int r = r0 + i * 8;     // n within tile
    __hip_bfloat16 h0 = __float2bfloat16(tile[kk][r]);
    __hip_bfloat16 h1 = __float2bfloat16(tile[kk + 1][r]);
    ushort2 u;
    u.x = *reinterpret_cast<ushort*>(&h0);
    u.y = *reinterpret_cast<ushort*>(&h1);
    *reinterpret_cast<ushort2*>(&wt[(size_t)(n0 + r) * K + (k0 + kk)]) = u;
  }
}

// -- kernel 3: R6 base (8-wave 128x256 split-K, one barrier/K-tile) ----------
// -- + T19 sched_group_barrier read/MFMA interleave, branch-free body --------
#define BM 128
#define BN 256
#define BK 64
#define LDS_HALF 24576   // ushorts per buffer (48 KB): A[128][64] + B[256][64]
#define B_OFF 8192

#define GLD16(g, l)                                              \
  __builtin_amdgcn_global_load_lds(                              \
      (const __attribute__((address_space(1))) void*)(g),        \
      (__attribute__((address_space(3))) void*)(l), 16, 0, 0)

__global__ __launch_bounds__(512, 2) void gemm_kernel(
    const __hip_bfloat16* __restrict__ A,   // [M][K] bf16
    const __hip_bfloat16* __restrict__ BT,  // [N][K] bf16
    const float* __restrict__ bias,         // [N]
    float* __restrict__ C,                  // [M][N]
    int M, int N, int K) {
  __shared__ ushort lds[3 * LDS_HALF];   // 144 KB, 3-deep circular

  const int NTM = M / BM;               // 16
  const int NTN = N / BN;               // 16
  const int nwg = NTM * NTN;            // 256

  // XCD-aware bijective swizzle (nwg % 8 == 0)
  int wg = (int)blockIdx.x;
  if ((nwg & 7) == 0) wg = (wg & 7) * (nwg >> 3) + (wg >> 3);
  const int nt = wg / NTM;
  const int mt = wg % NTM;
  const int m0 = mt * BM;
  const int n0 = nt * BN;

  const int tid = threadIdx.x;
  const int lane = tid & 63;
  const int wid = tid >> 6;   // 0..7
  const int kh = wid >> 2;    // k-half of each BK tile this wave consumes
  const int wq = wid & 3;     // N quarter; wave tile = 128 x 64 over K=32

  const ushort* Au = (const ushort*)A;
  const ushort* Bu = (const ushort*)BT;

  // ---- staging (pre-swizzled global source, linear LDS dest) ----
  // LDS[row][c16] holds global[row][c16 ^ (row&7)]
  const int l8 = lane >> 3;
  const int c16s = (lane & 7) ^ l8;
  // wave stages A rows [wid*16, +16) (2 chunks) and B rows [wid*32, +32) (4)
  const ushort* aS = Au + (size_t)(m0 + wid * 16 + l8) * K + c16s * 8;
  const ushort* bS = Bu + (size_t)(n0 + wid * 32 + l8) * K + c16s * 8;
  const int aD = (wid * 16) * 64;          // ushort offsets
  const int bD = B_OFF + (wid * 32) * 64;

  auto stage = [&](ushort* L, int t) {     // 6 gld_lds per wave = 6 KB
    const size_t to = (size_t)t * BK;
    GLD16(aS + to, L + aD);
    GLD16(aS + to + (size_t)8 * K, L + aD + 512);
    GLD16(bS + to, L + bD);
    GLD16(bS + to + (size_t)8 * K,  L + bD + 512);
    GLD16(bS + to + (size_t)16 * K, L + bD + 1024);
    GLD16(bS + to + (size_t)24 * K, L + bD + 1536);
  };

  // ---- fragment read addressing (swizzled ds_read); sck fixed per thread ---
  const int frow = lane & 15;
  const int lhi = lane >> 4;               // 0..3
  const int f7 = frow & 7;
  const int sck = ((kh * 4 + lhi) ^ f7) * 8;     // this wave's k-half columns
  const int aBase = frow * 64 + sck;             // a[mi] at aBase + mi*1024
  const int bBase = B_OFF + (wq * 64 + frow) * 64 + sck;  // b[ni] + ni*1024

  f32x4 acc[8][4];
#pragma unroll
  for (int i = 0; i < 8; ++i)
#pragma unroll
    for (int j = 0; j < 4; ++j)
#pragma unroll
      for (int r = 0; r < 4; ++r) acc[i][j][r] = 0.0f;

  // prologue: stage tiles 0,1; counted wait for tile 0 only
  stage(lds, 0);
  stage(lds + LDS_HALF, 1);
  asm volatile("s_waitcnt vmcnt(6)" ::: "memory");
  __builtin_amdgcn_s_barrier();

  const int NT = K / BK;   // 64
  int cur = 0;
  for (int t = 0; t < NT; ++t) {
    ushort* ldsCur = lds + cur * LDS_HALF;
    int nx = cur + 2; nx = (nx >= 3) ? nx - 3 : nx;
    int ts = t + 2;   ts = (ts < NT) ? ts : NT - 1;   // clamp: re-stage last
    // 12 ds_read_b128: B first, then A incrementally (SGB-pinned below)
    s16x8 b[4], a[8];
#pragma unroll
    for (int ni = 0; ni < 4; ++ni)
      b[ni] = *(const s16x8*)&ldsCur[bBase + ni * 1024];
#pragma unroll
    for (int mi = 0; mi < 8; ++mi)
      a[mi] = *(const s16x8*)&ldsCur[aBase + mi * 1024];
    // prefetch (unconditional, branch-free body -> one scheduling region)
    stage(lds + nx * LDS_HALF, ts);
    // 32 MFMA, mi-major: group mi needs only b0..3 + a[mi]
#pragma unroll
    for (int mi = 0; mi < 8; ++mi)
#pragma unroll
      for (int ni = 0; ni < 4; ++ni)
        acc[mi][ni] = __builtin_amdgcn_mfma_f32_16x16x32_bf16(
            a[mi], b[ni], acc[mi][ni], 0, 0, 0);
    // T19 schedule: 5 reads; {4 MFMA, 1 read}x7; 4 MFMA; 6 gld_lds
    __builtin_amdgcn_sched_group_barrier(0x100, 5, 0);
#pragma unroll
    for (int g = 0; g < 7; ++g) {
      __builtin_amdgcn_sched_group_barrier(0x8, 4, 0);
      __builtin_amdgcn_sched_group_barrier(0x100, 1, 0);
    }
    __builtin_amdgcn_sched_group_barrier(0x8, 4, 0);
    __builtin_amdgcn_sched_group_barrier(0x70, 6, 0);
    // counted: only t+2's 6 loads may remain in flight; t+1 guaranteed landed
    asm volatile("s_waitcnt vmcnt(6)" ::: "memory");
    __builtin_amdgcn_s_barrier();
    cur = cur + 1; cur = (cur == 3) ? 0 : cur;
  }

  // ---- epilogue: cross-k-half reduction through padded LDS, then store -----
  asm volatile("s_waitcnt vmcnt(0)" ::: "memory");  // drain tail stages
  __syncthreads();
  float* red = (float*)lds;                // 4 regions x [128][65] f32
  const int ccol = lane & 15;
  const int crow = lhi * 4;
  if (kh == 1) {
#pragma unroll
    for (int mi = 0; mi < 8; ++mi)
#pragma unroll
      for (int ni = 0; ni < 4; ++ni)
#pragma unroll
        for (int r = 0; r < 4; ++r)
          red[wq * 8320 + (mi * 16 + crow + r) * 65 + ni * 16 + ccol] =
              acc[mi][ni][r];
  }
  __syncthreads();
  if (kh == 0) {
#pragma unroll
    for (int ni = 0; ni < 4; ++ni) {
      const int gc = n0 + wq * 64 + ni * 16 + ccol;
      const float bv = HALF_N * bias[gc];
#pragma unroll
      for (int mi = 0; mi < 8; ++mi) {
        const int gr = m0 + mi * 16 + crow;
#pragma unroll
        for (int r = 0; r < 4; ++r)
          C[(size_t)(gr + r) * N + gc] =
              acc[mi][ni][r] +
              red[wq * 8320 + (mi * 16 + crow + r) * 65 + ni * 16 + ccol] + bv;
      }
    }
  }
}

extern "C" void kernel_launch(void* const* d_in, const int* in_sizes, int n_in,
                              void* d_out, int out_size, void* d_ws, size_t ws_size,
                              hipStream_t stream) {
  const float* x = (const float*)d_in[0];
  const float* w = (const float*)d_in[1];
  const float* b = (const float*)d_in[2];
  float* y = (float*)d_out;

  const int N = in_sizes[2];             // 4096
  const int K = in_sizes[1] / N;         // 4096
  const int M = in_sizes[0] / K;         // 2048

  __hip_bfloat16* Abf = (__hip_bfloat16*)d_ws;
  __hip_bfloat16* WT  = (__hip_bfloat16*)((char*)d_ws + (size_t)M * K * 2);
  if (ws_size < (size_t)M * K * 2 + (size_t)N * K * 2) return;  // need 48 MB

  // 1) A = 3.7 * clip(x)^log2(7.4) in bf16
  const int total4 = (M * K) / 4;
  fv_kernel<<<(total4 + 255) / 256, 256, 0, stream>>>(x, Abf, total4);

  // 2) WT = transpose(w) in bf16
  wt_kernel<<<dim3(N / 64, K / 64), dim3(256), 0, stream>>>(w, WT, K, N);

  // 3) y = A @ w + 3.7*b
  const int grid = (M / BM) * (N / BN);
  gemm_kernel<<<grid, 512, 0, stream>>>(Abf, WT, b, y, M, N, K);
}